// Round 8
// baseline (148.486 us; speedup 1.0000x reference)
//
#include <hip/hip_runtime.h>
#include <hip/hip_bf16.h>

// Problem constants (from reference)
#define NN  100000   // nodes
#define DF  128      // feature dim per table
#define HD  64       // hidden dim
#define NS  250000   // samples

// ---------------------------------------------------------------------------
// Algebra (R6/R8): out[s] = w2 . relu(u'[src] + v[dst]), where
//   Pn = [in1|in2] @ B  (M=100000, K=256, N=128), bf16 (25.6 MB, L3-resident)
//   Pn[n][0:64]  = u'[n] = in1[n]@W1a + in2[n]@W1c + b1   (b1 folded, R8)
//   Pn[n][64:128]= v [n] = in1[n]@W1b + in2[n]@W1d
//   B[k][n] = w1[(k>=128)*256 + (n>=64)*128 + (k&127)][n&63]
// R7 post-mortem: kernels now below harness reset fills (41 us) in top-5;
// ~75 us of wall is harness reset overhead (input restore + 268MB ws fill).
// R8: fold b1 into Pn, w2 packed bf16 -> edge does 4 VMEM/thread (was 6).
//
// Verified MFMA layouts (gfx950, learn_hip m89/m91):
//   A-frag: A[m=lane&15][k=(lane>>4)*8+j]   B-frag: B[n=lane&15][k=...]
//   C/D   : col=lane&15, row=(lane>>4)*4+reg
// LESSONS: train_sample is int32 on device; NS%32=16 -> clamp+predicate.
// ---------------------------------------------------------------------------

typedef __attribute__((ext_vector_type(8))) short bfrag;   // 8 bf16 = 4 VGPRs
typedef __attribute__((ext_vector_type(4))) float ffrag;   // 4 fp32 acc

__device__ __forceinline__ unsigned short bf16bits(float f) {
    __hip_bfloat16 b = __float2bfloat16(f);   // RNE
    return *(unsigned short*)&b;
}
__device__ __forceinline__ unsigned pack2(float a, float b) {
    return (unsigned)bf16bits(a) | ((unsigned)bf16bits(b) << 16);
}
__device__ __forceinline__ float bflo(unsigned u) {
    union { unsigned i; float f; } c; c.i = u << 16; return c.f;
}
__device__ __forceinline__ float bfhi(unsigned u) {
    union { unsigned i; float f; } c; c.i = u & 0xffff0000u; return c.f;
}

// ---- prep: pack B (256x128) into B-fragment-ordered bf16; pack w2 bf16 ----
// Bf[tn][ks][lane][j]: n = tn*16+(lane&15), k = ks*32+(lane>>4)*8+j
// gid 0..4095: Bf fragments. gid 4096..4159: w2bf[gid-4096].
__global__ __launch_bounds__(256) void prep_w1_kernel(
    const float* __restrict__ w1, const float* __restrict__ w2,
    unsigned short* __restrict__ Bf, unsigned short* __restrict__ w2bf)
{
    const int gid = blockIdx.x * 256 + threadIdx.x;
    if (gid >= 4096) {
        const int j = gid - 4096;
        if (j < HD) w2bf[j] = bf16bits(w2[j]);
        return;
    }
    const int lane = gid & 63;
    const int ks   = (gid >> 6) & 7;
    const int tn   = gid >> 9;

    const int n     = tn * 16 + (lane & 15);
    const int kbase = ks * 32 + (lane >> 4) * 8;
    const int col   = n & 63;

    uint4 u;
    unsigned p[4];
    #pragma unroll
    for (int jp = 0; jp < 4; ++jp) {
        float v[2];
        #pragma unroll
        for (int h = 0; h < 2; ++h) {
            const int k = kbase + jp * 2 + h;
            const int row = ((k >= 128) ? 256 : 0) + ((n >= 64) ? 128 : 0) + (k & 127);
            v[h] = w1[(size_t)row * HD + col];
        }
        p[jp] = pack2(v[0], v[1]);
    }
    u.x = p[0]; u.y = p[1]; u.z = p[2]; u.w = p[3];
    *(uint4*)(Bf + (size_t)gid * 8) = u;
}

// ---- phase 1: MFMA GEMM, 80 rows/block, K=256, N=128, b1 folded ----
// grid = 1250, block = 256 (4 waves). Wave w covers col tiles {2w, 2w+1},
// all 5 row-subtiles. A-frag LDS: subtile st at smem[st*4096] ([ks][lane][8]).
__global__ __launch_bounds__(256) void node_gemm_mfma(
    const float* __restrict__ in1,
    const float* __restrict__ in2,
    const unsigned short* __restrict__ Bf,
    const float* __restrict__ b1,
    unsigned short* __restrict__ Pn)         // [NN][128] bf16
{
    __shared__ unsigned short smem[20480];   // 40 KB

    const int t  = threadIdx.x;
    const int m0 = blockIdx.x * 80;

    // ---- b-frags first (independent of staging; overlaps with A loads) ----
    const int lane = t & 63;
    const int w    = t >> 6;
    bfrag bfr[2][8];
    #pragma unroll
    for (int ti = 0; ti < 2; ++ti) {
        const int tn = w * 2 + ti;
        #pragma unroll
        for (int ks = 0; ks < 8; ++ks)
            bfr[ti][ks] = *(const bfrag*)(Bf + ((size_t)(tn * 8 + ks) * 64 + lane) * 8);
    }

    // ---- stage A: 5 subtiles x (16 rows x 256 k), fp32 -> bf16 frag order --
    {
        const int r  = t >> 4;
        const int qq = t & 15;
        #pragma unroll
        for (int st = 0; st < 5; ++st) {
            const int row = m0 + st * 16 + r;
            const float* src = (qq < 8)
                ? in1 + (size_t)row * DF + qq * 16
                : in2 + (size_t)row * DF + (qq - 8) * 16;
            const float4 f0 = *(const float4*)(src);
            const float4 f1 = *(const float4*)(src + 4);
            const float4 f2 = *(const float4*)(src + 8);
            const float4 f3 = *(const float4*)(src + 12);
            uint4 u0, u1;
            u0.x = pack2(f0.x, f0.y); u0.y = pack2(f0.z, f0.w);
            u0.z = pack2(f1.x, f1.y); u0.w = pack2(f1.z, f1.w);
            u1.x = pack2(f2.x, f2.y); u1.y = pack2(f2.z, f2.w);
            u1.z = pack2(f3.x, f3.y); u1.w = pack2(f3.z, f3.w);
            const int g0 = qq * 2, g1 = qq * 2 + 1;
            *(uint4*)(&smem[st * 4096 + (g0 >> 2) * 512 + ((g0 & 3) * 16 + r) * 8]) = u0;
            *(uint4*)(&smem[st * 4096 + (g1 >> 2) * 512 + ((g1 & 3) * 16 + r) * 8]) = u1;
        }
    }
    __syncthreads();

    // ---- MFMA: ks-outer, subtile-inner -> 10 independent acc chains ----
    ffrag acc[5][2];
    #pragma unroll
    for (int st = 0; st < 5; ++st) {
        acc[st][0] = (ffrag){0.f, 0.f, 0.f, 0.f};
        acc[st][1] = (ffrag){0.f, 0.f, 0.f, 0.f};
    }
    #pragma unroll
    for (int ks = 0; ks < 8; ++ks) {
        #pragma unroll
        for (int st = 0; st < 5; ++st) {
            const bfrag af = *(const bfrag*)(&smem[st * 4096 + ks * 512 + lane * 8]);
            acc[st][0] = __builtin_amdgcn_mfma_f32_16x16x32_bf16(af, bfr[0][ks], acc[st][0], 0, 0, 0);
            acc[st][1] = __builtin_amdgcn_mfma_f32_16x16x32_bf16(af, bfr[1][ks], acc[st][1], 0, 0, 0);
        }
    }

    // ---- epilogue: (+b1 on n<64) -> bf16 LDS (80x128) -> coalesced stores --
    __syncthreads();
    {
        const int col = lane & 15;
        const int rq  = lane >> 4;
        // tiles 0..3 (w<2) are the u-half (n<64): fold b1. tiles 4..7: v-half.
        float badd[2];
        #pragma unroll
        for (int ti = 0; ti < 2; ++ti) {
            const int nc = (w * 2 + ti) * 16 + col;
            badd[ti] = (w < 2) ? b1[nc] : 0.f;
        }
        #pragma unroll
        for (int st = 0; st < 5; ++st) {
            #pragma unroll
            for (int ti = 0; ti < 2; ++ti) {
                const int nc = (w * 2 + ti) * 16 + col;
                #pragma unroll
                for (int reg = 0; reg < 4; ++reg)
                    smem[(st * 16 + rq * 4 + reg) * 128 + nc] =
                        bf16bits(acc[st][ti][reg] + badd[ti]);
            }
        }
    }
    __syncthreads();
    {
        #pragma unroll
        for (int i = 0; i < 5; ++i) {
            const int idx = i * 256 + t;        // 0..1279
            const int row = idx >> 4;           // 0..79
            const int seg = idx & 15;
            const uint4 u = *(const uint4*)(&smem[row * 128 + seg * 8]);
            *(uint4*)(Pn + (size_t)(m0 + row) * 128 + seg * 8) = u;
        }
    }
}

// ---- phase 2: out[s] = w2bf . relu(u'[src] + v[dst]) ----
// grid = 7813 (x32 samples, last clamped), block = 256.
// 8 lanes/sample, 8 cols/lane; 4 VMEM per thread (ts, u, v, w2).
__global__ __launch_bounds__(256) void edge_mlp_kernel(
    const unsigned short* __restrict__ Pn,
    const int*   __restrict__ ts,     // train_sample, int32
    const unsigned short* __restrict__ w2bf,   // 64 bf16
    float* __restrict__ out)          // (250000)
{
    const int t  = threadIdx.x;
    const int sr = blockIdx.x * 32 + (t >> 3);
    const int s  = min(sr, NS - 1);
    const int l  = t & 7;
    const int j  = l * 8;

    const int2 e = ((const int2*)ts)[s];
    const uint4 uu = *(const uint4*)(Pn + (size_t)e.x * 128 + j);       // u'+b1
    const uint4 vv = *(const uint4*)(Pn + (size_t)e.y * 128 + 64 + j);  // v
    const uint4 ww = *(const uint4*)(w2bf + j);

    float p = 0.f, x;
    x = bflo(uu.x) + bflo(vv.x); x = x > 0.f ? x : 0.f; p += x * bflo(ww.x);
    x = bfhi(uu.x) + bfhi(vv.x); x = x > 0.f ? x : 0.f; p += x * bfhi(ww.x);
    x = bflo(uu.y) + bflo(vv.y); x = x > 0.f ? x : 0.f; p += x * bflo(ww.y);
    x = bfhi(uu.y) + bfhi(vv.y); x = x > 0.f ? x : 0.f; p += x * bfhi(ww.y);
    x = bflo(uu.z) + bflo(vv.z); x = x > 0.f ? x : 0.f; p += x * bflo(ww.z);
    x = bfhi(uu.z) + bfhi(vv.z); x = x > 0.f ? x : 0.f; p += x * bfhi(ww.z);
    x = bflo(uu.w) + bflo(vv.w); x = x > 0.f ? x : 0.f; p += x * bflo(ww.w);
    x = bfhi(uu.w) + bfhi(vv.w); x = x > 0.f ? x : 0.f; p += x * bfhi(ww.w);

    p += __shfl_xor(p, 1);
    p += __shfl_xor(p, 2);
    p += __shfl_xor(p, 4);
    if (l == 0 && sr < NS) out[sr] = p;
}

extern "C" void kernel_launch(void* const* d_in, const int* in_sizes, int n_in,
                              void* d_out, int out_size, void* d_ws, size_t ws_size,
                              hipStream_t stream) {
    const float* in1 = (const float*)d_in[0];
    const float* in2 = (const float*)d_in[1];
    const int*   ts  = (const int*)  d_in[2];
    const float* w1  = (const float*)d_in[3];
    const float* b1  = (const float*)d_in[4];
    const float* w2  = (const float*)d_in[5];
    float* out = (float*)d_out;

    unsigned short* Pn = (unsigned short*)d_ws;     // 100000*128*2 = 25.6 MB
    const size_t Pbytes = (size_t)NN * 128 * sizeof(unsigned short);
    unsigned short* Bf;                             // 64 KB packed-B fragments
    unsigned short* w2bf;                           // 128 B packed w2
    if (ws_size >= Pbytes + 65536 + 128) {
        Bf   = (unsigned short*)((char*)d_ws + Pbytes);
        w2bf = (unsigned short*)((char*)d_ws + Pbytes + 65536);
    } else {
        // fallback: borrow d_out front (1 MB; fully overwritten by phase 2)
        Bf   = (unsigned short*)d_out;
        w2bf = (unsigned short*)((char*)d_out + 65536);
    }

    prep_w1_kernel<<<17, 256, 0, stream>>>(w1, w2, Bf, w2bf);
    node_gemm_mfma<<<NN / 80, 256, 0, stream>>>(in1, in2, Bf, b1, Pn);
    edge_mlp_kernel<<<(NS + 31) / 32, 256, 0, stream>>>(Pn, ts, w2bf, out);
}